// Round 10
// baseline (785.242 us; speedup 1.0000x reference)
//
#include <hip/hip_runtime.h>
#include <math.h>

// ComponentPointPredictor: ragged autoregressive point prediction.
// Round 10: r9's verified 3-barrier structure (NT=256, IT=4, 1024 blocks,
// wave q owns item q in Phase B+C), with the matvec switched fp64 -> fp32
// SPLIT-ACCUMULATOR (4 interleaved 64-term chains + in_W chain, combined
// in fp64). Rationale: rounds 3-9 plateau at 320-380us regardless of
// structure -> per-step fp64 FMA issue (4cyc) + fp64 LDS width is the
// floor. w-error budget doubles (~2e-6), but the dataset tolerates 1e-6
// with 200x margin (absmax 0.0234 vs threshold 5.12, rounds 2-9).
// s_hid/s_x stored fp32 (EXACT: tanh output / input data are fp32).
// The fp32 temp-50000 softmax -> soft-argmax -> floor chain stays
// op-for-op like the reference (round 2 lesson). No unroll pragmas on
// weight-load loops (r7/r8 lesson).

#define CTX     256
#define INIT    32
#define HID     256
#define WIN     63
#define MSTEPS  224            // CTX - INIT
#define OUTROW  (MSTEPS + CTX) // 480
#define IT      4
#define NT      256

__global__ void __launch_bounds__(NT)
cpp_kernel(const float* __restrict__ x,
           const float* __restrict__ hid_W,
           const float* __restrict__ hid_b,
           const float* __restrict__ in_W,
           const float* __restrict__ in_b,
           const float* __restrict__ pred_W,
           const float* __restrict__ pred_b,
           float* __restrict__ out)
{
    __shared__ float s_x[IT][CTX];       // 4 KB fp32 x rows (exact)
    __shared__ float s_hid[IT][HID];     // 4 KB fp32 hidden carry (exact: tanhf output)
    __shared__ int   s_lastl[IT];
    __shared__ int   s_act[IT];

    const int tid  = threadIdx.x;
    const int lane = tid & 63;
    const int q    = tid >> 6;           // wave 0..3 == slot owner
    const int j    = tid;                // hidden unit (NT == HID)
    const int item0 = blockIdx.x * IT;

    const double bias  = (double)hid_b[j] + (double)in_b[j];
    const float  pbias = (lane < WIN) ? pred_b[lane] : 0.0f;

    // ---- init: wave q loads item q's x row, zeroes its out row, hid=1 ----
    {
        const int item = item0 + q;
        float* orow = out + (size_t)item * OUTROW;
        for (int idx = lane; idx < OUTROW; idx += 64) orow[idx] = 0.0f;
        #pragma unroll
        for (int u = 0; u < 4; ++u)
            s_x[q][lane + 64 * u] = x[(size_t)item * CTX + lane + 64 * u];
        #pragma unroll
        for (int u = 0; u < 4; ++u) s_hid[q][lane + 64 * u] = 1.0f;
        if (lane == 0) { s_lastl[q] = INIT; s_act[q] = 1; }
    }

    float mylast = (float)INIT;          // wave-local (wave q owns item q)
    int   sc = 0;
    __syncthreads();

    for (int iter = 0; iter < MSTEPS; ++iter) {
        int lastl[IT], act[IT];
        #pragma unroll
        for (int it = 0; it < IT; ++it) { lastl[it] = s_lastl[it]; act[it] = s_act[it]; }
        if (!(act[0] | act[1] | act[2] | act[3])) break;

        // ---- Phase A: fp32 split-accumulator 288-dot for unit j, 4 items ----
        float ain[IT] = {0.0f, 0.0f, 0.0f, 0.0f};
        {
            int sb[IT];
            #pragma unroll
            for (int it = 0; it < IT; ++it) {
                int l = lastl[it]; if (l > CTX) l = CTX;
                sb[it] = l - INIT;                    // in [0, 224]
            }
            for (int m = 0; m < INIT; ++m) {
                const float wv = in_W[m * HID + j];
                #pragma unroll
                for (int it = 0; it < IT; ++it)
                    ain[it] = fmaf(s_x[it][sb[it] + m], wv, ain[it]);
            }
        }
        float ah[IT][4];
        #pragma unroll
        for (int it = 0; it < IT; ++it)
            #pragma unroll
            for (int u = 0; u < 4; ++u) ah[it][u] = 0.0f;

        for (int k = 0; k < HID; k += 4) {            // 4 independent chains/item
            const float w0 = hid_W[(size_t)(k + 0) * HID + j];
            const float w1 = hid_W[(size_t)(k + 1) * HID + j];
            const float w2 = hid_W[(size_t)(k + 2) * HID + j];
            const float w3 = hid_W[(size_t)(k + 3) * HID + j];
            #pragma unroll
            for (int it = 0; it < IT; ++it) {
                const float4 h = *(const float4*)&s_hid[it][k];
                ah[it][0] = fmaf(h.x, w0, ah[it][0]);
                ah[it][1] = fmaf(h.y, w1, ah[it][1]);
                ah[it][2] = fmaf(h.z, w2, ah[it][2]);
                ah[it][3] = fmaf(h.w, w3, ah[it][3]);
            }
        }
        __syncthreads();   // (1) all old-s_hid reads done

        #pragma unroll
        for (int it = 0; it < IT; ++it) {
            if (act[it]) {
                const double tot = bias + (double)ain[it]
                                 + (double)ah[it][0] + (double)ah[it][1]
                                 + (double)ah[it][2] + (double)ah[it][3];
                s_hid[it][j] = tanhf((float)tot);
            }
        }
        __syncthreads();   // (2) new hidden visible

        // ---- Phase B+C: wave q owns item q: w[lane], fp32 softmax chain ----
        if (act[q]) {
            const int it = q;
            float t = -INFINITY;
            if (lane < WIN) {
                float b0 = 0.0f, b1 = 0.0f, b2 = 0.0f, b3 = 0.0f;
                for (int k = 0; k < HID; k += 4) {
                    const float p0 = pred_W[(k + 0) * WIN + lane];
                    const float p1 = pred_W[(k + 1) * WIN + lane];
                    const float p2 = pred_W[(k + 2) * WIN + lane];
                    const float p3 = pred_W[(k + 3) * WIN + lane];
                    const float4 h = *(const float4*)&s_hid[it][k];
                    b0 = fmaf(h.x, p0, b0);
                    b1 = fmaf(h.y, p1, b1);
                    b2 = fmaf(h.z, p2, b2);
                    b3 = fmaf(h.w, p3, b3);
                }
                const double wv = (double)pbias + (double)b0 + (double)b1
                                + (double)b2 + (double)b3;
                t = (float)wv * 50000.0f;            // fp32 temp scale like ref
            }
            float mx = t;
            #pragma unroll
            for (int off = 32; off > 0; off >>= 1)
                mx = fmaxf(mx, __shfl_xor(mx, off));
            const float e = (lane < WIN) ? expf(t - mx) : 0.0f;
            float S = e;
            #pragma unroll
            for (int off = 32; off > 0; off >>= 1)
                S += __shfl_xor(S, off);
            const float p = e / S;
            float D = p * (float)lane;
            #pragma unroll
            for (int off = 32; off > 0; off >>= 1)
                D += __shfl_xor(D, off);
            float cur = fminf(D + 1.0f, 63.0f);
            float se = fminf(cur + mylast, 256.0f);
            const int sel = (int)se;

            float* orow = out + (size_t)(item0 + it) * OUTROW;
            if (lane < WIN) {
                const int pos = lastl[it] + lane;
                if (pos < sel) {
                    const float msk = 1.0f / (1.0f + expf((float)lane - cur));
                    orow[MSTEPS + pos] = msk * s_x[it][pos];
                }
            }
            const bool done = (se >= 256.0f);        // final step's pt is dropped
            if (lane == 0) {
                if (!done) { orow[sc] = se; s_lastl[it] = sel; }
                else       { s_act[it] = 0; }
            }
            sc++;
            mylast = se;
        }
        __syncthreads();   // (3) state updates visible for next Phase A
    }
}

extern "C" void kernel_launch(void* const* d_in, const int* in_sizes, int n_in,
                              void* d_out, int out_size, void* d_ws, size_t ws_size,
                              hipStream_t stream) {
    const float* x      = (const float*)d_in[0];
    const float* hid_W  = (const float*)d_in[1];
    const float* hid_b  = (const float*)d_in[2];
    const float* in_W   = (const float*)d_in[3];
    const float* in_b   = (const float*)d_in[4];
    const float* pred_W = (const float*)d_in[5];
    const float* pred_b = (const float*)d_in[6];
    float* out = (float*)d_out;

    const int B = in_sizes[0] / CTX;     // 4096
    const int nblocks = B / IT;          // 1024
    cpp_kernel<<<nblocks, NT, 0, stream>>>(x, hid_W, hid_b, in_W, in_b,
                                           pred_W, pred_b, out);
}

// Round 11
// 342.496 us; speedup vs baseline: 2.2927x; 2.2927x over previous
//
#include <hip/hip_runtime.h>
#include <math.h>

// ComponentPointPredictor: ragged autoregressive point prediction.
// Round 11: r10's fp32 split-accumulator arithmetic (VALIDATED: absmax
// 0.039 vs threshold 5.12) with codegen pinned back to r9's proven shape.
// r10 regressed 332->785us because the compiler auto-unrolled the fp32
// k-loops x4, batching ~16 weight loads behind one waitcnt wall (r7/r8
// signature) -> VGPR 148 -> 3 waves/SIMD -> L2 latency exposed.
// Fixes: #pragma unroll 1 on both weight-stream loops (rolled 4-load/iter
// form pipelines well: r4/r9 at VALUBusy 42-47%), __launch_bounds__(256,4)
// as a 128-VGPR backstop.
// Numerics: fp32 split-accumulator matvec (4 chains + in_W chain, summed
// in fp64) -- bit-identical to r10; fp32 temp-50000 softmax -> soft-argmax
// -> floor chain op-for-op like the reference (round 2 lesson).

#define CTX     256
#define INIT    32
#define HID     256
#define WIN     63
#define MSTEPS  224            // CTX - INIT
#define OUTROW  (MSTEPS + CTX) // 480
#define IT      4
#define NT      256

__global__ void __launch_bounds__(NT, 4)
cpp_kernel(const float* __restrict__ x,
           const float* __restrict__ hid_W,
           const float* __restrict__ hid_b,
           const float* __restrict__ in_W,
           const float* __restrict__ in_b,
           const float* __restrict__ pred_W,
           const float* __restrict__ pred_b,
           float* __restrict__ out)
{
    __shared__ float s_x[IT][CTX];       // 4 KB fp32 x rows (exact)
    __shared__ float s_hid[IT][HID];     // 4 KB fp32 hidden carry (exact: tanhf output)
    __shared__ int   s_lastl[IT];
    __shared__ int   s_act[IT];

    const int tid  = threadIdx.x;
    const int lane = tid & 63;
    const int q    = tid >> 6;           // wave 0..3 == slot owner
    const int j    = tid;                // hidden unit (NT == HID)
    const int item0 = blockIdx.x * IT;

    const double bias  = (double)hid_b[j] + (double)in_b[j];
    const float  pbias = (lane < WIN) ? pred_b[lane] : 0.0f;

    // ---- init: wave q loads item q's x row, zeroes its out row, hid=1 ----
    {
        const int item = item0 + q;
        float* orow = out + (size_t)item * OUTROW;
        for (int idx = lane; idx < OUTROW; idx += 64) orow[idx] = 0.0f;
        #pragma unroll
        for (int u = 0; u < 4; ++u)
            s_x[q][lane + 64 * u] = x[(size_t)item * CTX + lane + 64 * u];
        #pragma unroll
        for (int u = 0; u < 4; ++u) s_hid[q][lane + 64 * u] = 1.0f;
        if (lane == 0) { s_lastl[q] = INIT; s_act[q] = 1; }
    }

    float mylast = (float)INIT;          // wave-local (wave q owns item q)
    int   sc = 0;
    __syncthreads();

    for (int iter = 0; iter < MSTEPS; ++iter) {
        int lastl[IT], act[IT];
        #pragma unroll
        for (int it = 0; it < IT; ++it) { lastl[it] = s_lastl[it]; act[it] = s_act[it]; }
        if (!(act[0] | act[1] | act[2] | act[3])) break;

        // ---- Phase A: fp32 split-accumulator 288-dot for unit j, 4 items ----
        float ain[IT] = {0.0f, 0.0f, 0.0f, 0.0f};
        {
            int sb[IT];
            #pragma unroll
            for (int it = 0; it < IT; ++it) {
                int l = lastl[it]; if (l > CTX) l = CTX;
                sb[it] = l - INIT;                    // in [0, 224]
            }
            #pragma unroll 1
            for (int m = 0; m < INIT; ++m) {
                const float wv = in_W[m * HID + j];
                #pragma unroll
                for (int it = 0; it < IT; ++it)
                    ain[it] = fmaf(s_x[it][sb[it] + m], wv, ain[it]);
            }
        }
        float ah[IT][4];
        #pragma unroll
        for (int it = 0; it < IT; ++it)
            #pragma unroll
            for (int u = 0; u < 4; ++u) ah[it][u] = 0.0f;

        #pragma unroll 1
        for (int k = 0; k < HID; k += 4) {            // rolled: 4 loads + 16 FMA
            const float w0 = hid_W[(size_t)(k + 0) * HID + j];
            const float w1 = hid_W[(size_t)(k + 1) * HID + j];
            const float w2 = hid_W[(size_t)(k + 2) * HID + j];
            const float w3 = hid_W[(size_t)(k + 3) * HID + j];
            #pragma unroll
            for (int it = 0; it < IT; ++it) {
                const float4 h = *(const float4*)&s_hid[it][k];
                ah[it][0] = fmaf(h.x, w0, ah[it][0]);
                ah[it][1] = fmaf(h.y, w1, ah[it][1]);
                ah[it][2] = fmaf(h.z, w2, ah[it][2]);
                ah[it][3] = fmaf(h.w, w3, ah[it][3]);
            }
        }
        __syncthreads();   // (1) all old-s_hid reads done

        #pragma unroll
        for (int it = 0; it < IT; ++it) {
            if (act[it]) {
                const double tot = bias + (double)ain[it]
                                 + (double)ah[it][0] + (double)ah[it][1]
                                 + (double)ah[it][2] + (double)ah[it][3];
                s_hid[it][j] = tanhf((float)tot);
            }
        }
        __syncthreads();   // (2) new hidden visible

        // ---- Phase B+C: wave q owns item q: w[lane], fp32 softmax chain ----
        if (act[q]) {
            const int it = q;
            float t = -INFINITY;
            if (lane < WIN) {
                float b0 = 0.0f, b1 = 0.0f, b2 = 0.0f, b3 = 0.0f;
                #pragma unroll 1
                for (int k = 0; k < HID; k += 4) {
                    const float p0 = pred_W[(k + 0) * WIN + lane];
                    const float p1 = pred_W[(k + 1) * WIN + lane];
                    const float p2 = pred_W[(k + 2) * WIN + lane];
                    const float p3 = pred_W[(k + 3) * WIN + lane];
                    const float4 h = *(const float4*)&s_hid[it][k];
                    b0 = fmaf(h.x, p0, b0);
                    b1 = fmaf(h.y, p1, b1);
                    b2 = fmaf(h.z, p2, b2);
                    b3 = fmaf(h.w, p3, b3);
                }
                const double wv = (double)pbias + (double)b0 + (double)b1
                                + (double)b2 + (double)b3;
                t = (float)wv * 50000.0f;            // fp32 temp scale like ref
            }
            float mx = t;
            #pragma unroll
            for (int off = 32; off > 0; off >>= 1)
                mx = fmaxf(mx, __shfl_xor(mx, off));
            const float e = (lane < WIN) ? expf(t - mx) : 0.0f;
            float S = e;
            #pragma unroll
            for (int off = 32; off > 0; off >>= 1)
                S += __shfl_xor(S, off);
            const float p = e / S;
            float D = p * (float)lane;
            #pragma unroll
            for (int off = 32; off > 0; off >>= 1)
                D += __shfl_xor(D, off);
            float cur = fminf(D + 1.0f, 63.0f);
            float se = fminf(cur + mylast, 256.0f);
            const int sel = (int)se;

            float* orow = out + (size_t)(item0 + it) * OUTROW;
            if (lane < WIN) {
                const int pos = lastl[it] + lane;
                if (pos < sel) {
                    const float msk = 1.0f / (1.0f + expf((float)lane - cur));
                    orow[MSTEPS + pos] = msk * s_x[it][pos];
                }
            }
            const bool done = (se >= 256.0f);        // final step's pt is dropped
            if (lane == 0) {
                if (!done) { orow[sc] = se; s_lastl[it] = sel; }
                else       { s_act[it] = 0; }
            }
            sc++;
            mylast = se;
        }
        __syncthreads();   // (3) state updates visible for next Phase A
    }
}

extern "C" void kernel_launch(void* const* d_in, const int* in_sizes, int n_in,
                              void* d_out, int out_size, void* d_ws, size_t ws_size,
                              hipStream_t stream) {
    const float* x      = (const float*)d_in[0];
    const float* hid_W  = (const float*)d_in[1];
    const float* hid_b  = (const float*)d_in[2];
    const float* in_W   = (const float*)d_in[3];
    const float* in_b   = (const float*)d_in[4];
    const float* pred_W = (const float*)d_in[5];
    const float* pred_b = (const float*)d_in[6];
    float* out = (float*)d_out;

    const int B = in_sizes[0] / CTX;     // 4096
    const int nblocks = B / IT;          // 1024
    cpp_kernel<<<nblocks, NT, 0, stream>>>(x, hid_W, hid_b, in_W, in_b,
                                           pred_W, pred_b, out);
}